// Round 1
// baseline (440.498 us; speedup 1.0000x reference)
//
#include <hip/hip_runtime.h>
#include <cstdint>

constexpr int NCOLS   = 4096;
constexpr int THREADS = 256;
constexpr int EPT     = NCOLS / THREADS;  // 16 elements per thread
constexpr int KSEL    = 65;               // need 65th largest (and 64th)

// Soft-threshold preserving sign.
__device__ __forceinline__ float soft(float x, float Q) {
    float r = fmaxf(fabsf(x) - Q, 0.0f);
    return copysignf(r, x);
}

__global__ __launch_bounds__(THREADS) void topk_sparsify(
    const float* __restrict__ X, float* __restrict__ out, int rows)
{
    const int row = blockIdx.x;
    if (row >= rows) return;
    const int t = threadIdx.x;

    const float4* __restrict__ x4 = reinterpret_cast<const float4*>(X + (size_t)row * NCOLS);
    float4* __restrict__       o4 = reinterpret_cast<float4*>(out + (size_t)row * NCOLS);

    // ---- Load row: 4 float4 per thread, coalesced (thread t gets chunks t, t+256, ...)
    float4 d[4];
#pragma unroll
    for (int i = 0; i < 4; ++i) d[i] = x4[t + THREADS * i];

    // abs bit patterns (unsigned compare == float compare for non-negative)
    uint32_t a[EPT];
#pragma unroll
    for (int i = 0; i < 4; ++i) {
        a[4*i+0] = __float_as_uint(d[i].x) & 0x7FFFFFFFu;
        a[4*i+1] = __float_as_uint(d[i].y) & 0x7FFFFFFFu;
        a[4*i+2] = __float_as_uint(d[i].z) & 0x7FFFFFFFu;
        a[4*i+3] = __float_as_uint(d[i].w) & 0x7FFFFFFFu;
    }

    __shared__ uint32_t hist[2048];
    __shared__ uint32_t scan[THREADS];
    __shared__ uint32_t sel_digit_s;
    __shared__ uint32_t sel_k_s;
    __shared__ uint32_t wcnt[4], wmn[4];
    __shared__ float    q_sh;

    uint32_t known = 0;   // known high bits of the 65th-largest pattern
    uint32_t k     = KSEL;

    // Pass configs: bits [30:20] (11b, 2048 bins), [19:10] (10b), [9:0] (10b).
    const int      shifts[3] = {20, 10, 0};
    const uint32_t dmask [3] = {0x7FFu, 0x3FFu, 0x3FFu};
    const int      nbins [3] = {2048, 1024, 1024};
    const uint32_t pmask [3] = {0u, 0xFFF00000u, 0xFFFFFC00u};

#pragma unroll
    for (int p = 0; p < 3; ++p) {
        const int      sh = shifts[p];
        const uint32_t dm = dmask[p];
        const int      nb = nbins[p];
        const uint32_t pm = pmask[p];

        // zero histogram
        for (int b = t; b < nb; b += THREADS) hist[b] = 0u;
        __syncthreads();

        // accumulate (pass 0: all elements; later passes: prefix-matching only)
#pragma unroll
        for (int i = 0; i < EPT; ++i) {
            if ((a[i] & pm) == known) {
                atomicAdd(&hist[(a[i] >> sh) & dm], 1u);
            }
        }
        __syncthreads();

        // per-thread group sums (groups of nb/THREADS consecutive bins)
        const int gpb  = nb / THREADS;   // 8 or 4
        const int base = t * gpb;
        uint32_t gsum = 0;
        for (int j = 0; j < gpb; ++j) gsum += hist[base + j];
        scan[t] = gsum;
        __syncthreads();

        // Hillis-Steele inclusive SUFFIX scan over 256 group sums
        for (int off = 1; off < THREADS; off <<= 1) {
            uint32_t val = scan[t];
            if (t + off < THREADS) val += scan[t + off];
            __syncthreads();
            scan[t] = val;
            __syncthreads();
        }
        const uint32_t above = (t + 1 < THREADS) ? scan[t + 1] : 0u;

        // find the bin where descending rank k lands: G < k <= G + hist[bin]
        uint32_t G = above;
        for (int j = gpb - 1; j >= 0; --j) {
            const uint32_t c = hist[base + j];
            if (G < k && k <= G + c) {
                sel_digit_s = (uint32_t)(base + j);
                sel_k_s     = k - G;
            }
            G += c;
        }
        __syncthreads();
        known |= sel_digit_s << sh;
        k = sel_k_s;
        __syncthreads();   // all reads of sel_* done before next pass rewrites
    }

    const uint32_t b65 = known;            // bit pattern of 65th largest
    const float    v65 = __uint_as_float(b65);

    // ---- find 64th largest: min of elements strictly > b65 (if exactly 64 exist)
    uint32_t cnt = 0, mn = 0xFFFFFFFFu;
#pragma unroll
    for (int i = 0; i < EPT; ++i) {
        if (a[i] > b65) { cnt++; mn = min(mn, a[i]); }
    }
#pragma unroll
    for (int off = 32; off >= 1; off >>= 1) {
        cnt += __shfl_down(cnt, off, 64);
        uint32_t m2 = __shfl_down(mn, off, 64);
        mn = min(mn, m2);
    }
    const int wave = t >> 6, lane = t & 63;
    if (lane == 0) { wcnt[wave] = cnt; wmn[wave] = mn; }
    __syncthreads();
    if (t == 0) {
        uint32_t C = wcnt[0] + wcnt[1] + wcnt[2] + wcnt[3];
        uint32_t M = min(min(wmn[0], wmn[1]), min(wmn[2], wmn[3]));
        float v64 = (C == 64u) ? __uint_as_float(M) : v65;
        // Q = v65 + frac*(v64 - v65), frac = 0.015625 (exact in binary)
        q_sh = fmaf(0.015625f, v64 - v65, v65);
    }
    __syncthreads();
    const float Q = q_sh;

    // ---- write output, coalesced float4
#pragma unroll
    for (int i = 0; i < 4; ++i) {
        float4 f = d[i];
        f.x = soft(f.x, Q);
        f.y = soft(f.y, Q);
        f.z = soft(f.z, Q);
        f.w = soft(f.w, Q);
        o4[t + THREADS * i] = f;
    }
}

extern "C" void kernel_launch(void* const* d_in, const int* in_sizes, int n_in,
                              void* d_out, int out_size, void* d_ws, size_t ws_size,
                              hipStream_t stream) {
    const float* X  = (const float*)d_in[0];
    float*       out = (float*)d_out;
    const int rows = in_sizes[0] / NCOLS;   // 16384
    topk_sparsify<<<rows, THREADS, 0, stream>>>(X, out, rows);
}